// Round 3
// baseline (637.635 us; speedup 1.0000x reference)
//
#include <hip/hip_runtime.h>

#define NS 128                 // samples per ray
#define NEAR_P 2.0f
#define FAR_P  6.0f

typedef float f32x4 __attribute__((ext_vector_type(4)));  // clang vector type: valid for nontemporal builtins

// 4 rays per wave: 16 lanes per ray, 8 samples per lane.
// Lane k of a ray group handles samples [8k, 8k+7].
// Inputs are streamed exactly once -> nontemporal loads (bypass cache allocate).
__global__ __launch_bounds__(256) void volrender_kernel(
    const float* __restrict__ sigmas,      // [nrays, 128]
    const float* __restrict__ radiances,   // [nrays, 128, 3]
    float* __restrict__ out_rgb,           // [nrays, 3]
    float* __restrict__ out_depth,         // [nrays]
    int nrays)
{
    const int lane = threadIdx.x & 63;
    const int wave = threadIdx.x >> 6;
    const int grp  = lane >> 4;            // which ray within the wave (0..3)
    const int k    = lane & 15;            // lane within the ray (0..15)

    const int ray = (((blockIdx.x << 2) + wave) << 2) + grp;   // 16 rays / block
    if (ray >= nrays) return;

    const float dz = (FAR_P - NEAR_P) / (float)(NS - 1);

    const float* sig = sigmas    + (size_t)ray * NS + 8 * k;
    const float* rad = radiances + (size_t)ray * NS * 3 + 24 * k;

    // ---- loads: 8 sigmas + 24 radiance floats per lane, all dwordx4, nontemporal ----
    const f32x4 s0 = __builtin_nontemporal_load((const f32x4*)(sig));
    const f32x4 s1 = __builtin_nontemporal_load((const f32x4*)(sig + 4));
    const f32x4 r0 = __builtin_nontemporal_load((const f32x4*)(rad));
    const f32x4 r1 = __builtin_nontemporal_load((const f32x4*)(rad + 4));
    const f32x4 r2 = __builtin_nontemporal_load((const f32x4*)(rad + 8));
    const f32x4 r3 = __builtin_nontemporal_load((const f32x4*)(rad + 12));
    const f32x4 r4 = __builtin_nontemporal_load((const f32x4*)(rad + 16));
    const f32x4 r5 = __builtin_nontemporal_load((const f32x4*)(rad + 20));

    const float sv[8]  = {s0.x, s0.y, s0.z, s0.w, s1.x, s1.y, s1.z, s1.w};
    const float rv[24] = {r0.x, r0.y, r0.z, r0.w,
                          r1.x, r1.y, r1.z, r1.w,
                          r2.x, r2.y, r2.z, r2.w,
                          r3.x, r3.y, r3.z, r3.w,
                          r4.x, r4.y, r4.z, r4.w,
                          r5.x, r5.y, r5.z, r5.w};

    // t_s = exp(-sigma*dist) + 1e-10 ; a_s = 1 - exp(-sigma*dist)
    float a[8], t[8];
    #pragma unroll
    for (int s = 0; s < 8; ++s) {
        const float d = (k == 15 && s == 7) ? 1e10f : dz;   // last interval open
        const float e = __expf(-sv[s] * d);
        a[s] = 1.0f - e;
        t[s] = e + 1e-10f;
    }

    // local product of this lane's 8 transmittance steps (tree, short dep chain)
    const float p01 = t[0] * t[1], p23 = t[2] * t[3];
    const float p45 = t[4] * t[5], p67 = t[6] * t[7];
    float p = (p01 * p23) * (p45 * p67);

    // inclusive prefix product across the 16 lanes of this ray (4 steps)
    float incl = p;
    #pragma unroll
    for (int off = 1; off < 16; off <<= 1) {
        const float v = __shfl_up(incl, off, 16);
        if (k >= off) incl *= v;
    }
    // exclusive prefix (product of all steps in preceding lanes)
    float excl = __shfl_up(incl, 1, 16);
    if (k == 0) excl = 1.0f;

    // within-lane inclusive cumprod, weights, partial sums
    float T  = excl;
    float pr = 0.0f, pg = 0.0f, pb = 0.0f, pd = 0.0f;
    const float z0 = NEAR_P + (float)(8 * k) * dz;
    #pragma unroll
    for (int s = 0; s < 8; ++s) {
        T *= t[s];                         // inclusive cumprod at sample s
        const float w = a[s] * T;
        pr += w * rv[3 * s + 0];
        pg += w * rv[3 * s + 1];
        pb += w * rv[3 * s + 2];
        pd += w * (z0 + (float)s * dz);
    }

    // tree-reduce across the 16 lanes of this ray (4 steps x 4 values)
    #pragma unroll
    for (int off = 8; off > 0; off >>= 1) {
        pr += __shfl_down(pr, off, 16);
        pg += __shfl_down(pg, off, 16);
        pb += __shfl_down(pb, off, 16);
        pd += __shfl_down(pd, off, 16);
    }

    if (k == 0) {
        float* o = out_rgb + (size_t)ray * 3;
        o[0] = pr;
        o[1] = pg;
        o[2] = pb;
        out_depth[ray] = pd;
    }
}

extern "C" void kernel_launch(void* const* d_in, const int* in_sizes, int n_in,
                              void* d_out, int out_size, void* d_ws, size_t ws_size,
                              hipStream_t stream) {
    const float* sigmas    = (const float*)d_in[0];
    const float* radiances = (const float*)d_in[1];
    float* out = (float*)d_out;

    const int nrays = in_sizes[0] / NS;        // B * NUM_RAYS = 262144
    float* out_rgb   = out;                    // [nrays, 3]
    float* out_depth = out + (size_t)nrays * 3;

    const int raysPerBlock = 16;               // 4 waves x 4 rays/wave
    const int grid = (nrays + raysPerBlock - 1) / raysPerBlock;
    volrender_kernel<<<grid, 256, 0, stream>>>(sigmas, radiances, out_rgb, out_depth, nrays);
}

// Round 4
// 582.378 us; speedup vs baseline: 1.0949x; 1.0949x over previous
//
#include <hip/hip_runtime.h>

#define NS 128                 // samples per ray
#define NEAR_P 2.0f
#define FAR_P  6.0f

// 4 rays per wave: 16 lanes per ray, 8 samples per lane.
// Lane k of a ray group handles samples [8k, 8k+7].
// NOTE: plain (cached) loads — nontemporal loads measured +52us regression
// (R3: 638us vs 586us): harness fill leaves input partially L2/L3-resident,
// and nt bypasses those hits.
__global__ __launch_bounds__(256) void volrender_kernel(
    const float* __restrict__ sigmas,      // [nrays, 128]
    const float* __restrict__ radiances,   // [nrays, 128, 3]
    float* __restrict__ out_rgb,           // [nrays, 3]
    float* __restrict__ out_depth,         // [nrays]
    int nrays)
{
    const int lane = threadIdx.x & 63;
    const int wave = threadIdx.x >> 6;
    const int grp  = lane >> 4;            // which ray within the wave (0..3)
    const int k    = lane & 15;            // lane within the ray (0..15)

    const int ray = (((blockIdx.x << 2) + wave) << 2) + grp;   // 16 rays / block
    if (ray >= nrays) return;

    const float dz = (FAR_P - NEAR_P) / (float)(NS - 1);

    const float* sig = sigmas    + (size_t)ray * NS + 8 * k;
    const float* rad = radiances + (size_t)ray * NS * 3 + 24 * k;

    // ---- loads: 8 sigmas + 24 radiance floats per lane, all dwordx4 ----
    const float4 s0 = *(const float4*)(sig);
    const float4 s1 = *(const float4*)(sig + 4);
    const float4 r0 = *(const float4*)(rad);
    const float4 r1 = *(const float4*)(rad + 4);
    const float4 r2 = *(const float4*)(rad + 8);
    const float4 r3 = *(const float4*)(rad + 12);
    const float4 r4 = *(const float4*)(rad + 16);
    const float4 r5 = *(const float4*)(rad + 20);

    const float sv[8]  = {s0.x, s0.y, s0.z, s0.w, s1.x, s1.y, s1.z, s1.w};
    const float rv[24] = {r0.x, r0.y, r0.z, r0.w,
                          r1.x, r1.y, r1.z, r1.w,
                          r2.x, r2.y, r2.z, r2.w,
                          r3.x, r3.y, r3.z, r3.w,
                          r4.x, r4.y, r4.z, r4.w,
                          r5.x, r5.y, r5.z, r5.w};

    // t_s = exp(-sigma*dist) + 1e-10 ; a_s = 1 - exp(-sigma*dist)
    float a[8], t[8];
    #pragma unroll
    for (int s = 0; s < 8; ++s) {
        const float d = (k == 15 && s == 7) ? 1e10f : dz;   // last interval open
        const float e = __expf(-sv[s] * d);
        a[s] = 1.0f - e;
        t[s] = e + 1e-10f;
    }

    // local product of this lane's 8 transmittance steps (tree, short dep chain)
    const float p01 = t[0] * t[1], p23 = t[2] * t[3];
    const float p45 = t[4] * t[5], p67 = t[6] * t[7];
    float p = (p01 * p23) * (p45 * p67);

    // inclusive prefix product across the 16 lanes of this ray (4 steps)
    float incl = p;
    #pragma unroll
    for (int off = 1; off < 16; off <<= 1) {
        const float v = __shfl_up(incl, off, 16);
        if (k >= off) incl *= v;
    }
    // exclusive prefix (product of all steps in preceding lanes)
    float excl = __shfl_up(incl, 1, 16);
    if (k == 0) excl = 1.0f;

    // within-lane inclusive cumprod, weights, partial sums
    float T  = excl;
    float pr = 0.0f, pg = 0.0f, pb = 0.0f, pd = 0.0f;
    const float z0 = NEAR_P + (float)(8 * k) * dz;
    #pragma unroll
    for (int s = 0; s < 8; ++s) {
        T *= t[s];                         // inclusive cumprod at sample s
        const float w = a[s] * T;
        pr += w * rv[3 * s + 0];
        pg += w * rv[3 * s + 1];
        pb += w * rv[3 * s + 2];
        pd += w * (z0 + (float)s * dz);
    }

    // tree-reduce across the 16 lanes of this ray (4 steps x 4 values)
    #pragma unroll
    for (int off = 8; off > 0; off >>= 1) {
        pr += __shfl_down(pr, off, 16);
        pg += __shfl_down(pg, off, 16);
        pb += __shfl_down(pb, off, 16);
        pd += __shfl_down(pd, off, 16);
    }

    if (k == 0) {
        float* o = out_rgb + (size_t)ray * 3;
        o[0] = pr;
        o[1] = pg;
        o[2] = pb;
        out_depth[ray] = pd;
    }
}

extern "C" void kernel_launch(void* const* d_in, const int* in_sizes, int n_in,
                              void* d_out, int out_size, void* d_ws, size_t ws_size,
                              hipStream_t stream) {
    const float* sigmas    = (const float*)d_in[0];
    const float* radiances = (const float*)d_in[1];
    float* out = (float*)d_out;

    const int nrays = in_sizes[0] / NS;        // B * NUM_RAYS = 262144
    float* out_rgb   = out;                    // [nrays, 3]
    float* out_depth = out + (size_t)nrays * 3;

    const int raysPerBlock = 16;               // 4 waves x 4 rays/wave
    const int grid = (nrays + raysPerBlock - 1) / raysPerBlock;
    volrender_kernel<<<grid, 256, 0, stream>>>(sigmas, radiances, out_rgb, out_depth, nrays);
}